// Round 2
// baseline (35.379 us; speedup 1.0000x reference)
//
#include <hip/hip_runtime.h>

#define B_DIM 256
#define L_DIM 32768
#define CHUNK 2048
#define HALO  100
#define NTOT  (CHUNK + 2*HALO)   // 2248
#define T     256
#define EPT   9                  // ceil(NTOT / T)

__global__ __launch_bounds__(T) void pool_feat_kernel(const float* __restrict__ x,
                                                      float* __restrict__ out) {
    const int row    = blockIdx.y;
    const int chunk0 = blockIdx.x * CHUNK;
    const int tid    = threadIdx.x;

    __shared__ float sA[NTOT];
    __shared__ float sB[NTOT];
    __shared__ float waveA[4];
    __shared__ float waveB[4];

    const float* xr = x + (size_t)row * L_DIM;

    // Phase 1: coalesced load + transform (zero-fill outside the row)
    for (int j = tid; j < NTOT; j += T) {
        int col = chunk0 - HALO + j;
        float v = (col >= 0 && col < L_DIM) ? xr[col] : 0.0f;
        sA[j] = logf(fmaxf(1.0f, 1.0f + v));
        sB[j] = logf(fmaxf(1.0f, 1.0f - v));
    }
    __syncthreads();

    // Phase 2: per-thread sequential inclusive cumsum over its segment
    const int s0 = tid * EPT;
    const int s1 = min(NTOT, s0 + EPT);
    float runA = 0.0f, runB = 0.0f;
    for (int j = s0; j < s1; ++j) {
        runA += sA[j]; sA[j] = runA;
        runB += sB[j]; sB[j] = runB;
    }

    // Phase 3: scan segment totals across the block (wave shuffle + wave totals)
    float vA = runA, vB = runB;
    const int lane = tid & 63;
    const int wid  = tid >> 6;
    #pragma unroll
    for (int d = 1; d < 64; d <<= 1) {
        float uA = __shfl_up(vA, d);
        float uB = __shfl_up(vB, d);
        if (lane >= d) { vA += uA; vB += uB; }
    }
    if (lane == 63) { waveA[wid] = vA; waveB[wid] = vB; }
    __syncthreads();
    float offA = vA - runA;   // exclusive prefix within wave
    float offB = vB - runB;
    for (int w = 0; w < wid; ++w) { offA += waveA[w]; offB += waveB[w]; }

    // Phase 4: apply cross-segment offsets in place
    for (int j = s0; j < s1; ++j) { sA[j] += offA; sB[j] += offB; }
    __syncthreads();

    // Phase 5: windowed sums from cumsum, 4 coalesced output planes.
    // Local inclusive cumsum cs[j] covers cols [chunk0-100 .. chunk0-100+j].
    // Output i (col = chunk0+i, local li = i+100):
    //   sum199 over local [i+1,  i+199] = cs[i+199] - cs[i]
    //   sum3   over local [i+99, i+101] = cs[i+101] - cs[i+98]
    const float inv3   = 1.0f / 3.0f;
    const float inv199 = 1.0f / 199.0f;
    const size_t outbase = (size_t)row * 4u * L_DIM;
    for (int i = tid; i < CHUNK; i += T) {
        const int col = chunk0 + i;
        float sum199a = sA[i + 199] - sA[i];
        float sum3a   = sA[i + 101] - sA[i + 98];
        float sum199b = sB[i + 199] - sB[i];
        float sum3b   = sB[i + 101] - sB[i + 98];
        float a0 = sum3a * inv3, a5 = sum199a * inv199;
        float b0 = sum3b * inv3, b5 = sum199b * inv199;
        out[outbase + 0u * L_DIM + col] = a0 - a5;
        out[outbase + 1u * L_DIM + col] = a0;
        out[outbase + 2u * L_DIM + col] = b0 - b5;
        out[outbase + 3u * L_DIM + col] = b0;
    }
}

extern "C" void kernel_launch(void* const* d_in, const int* in_sizes, int n_in,
                              void* d_out, int out_size, void* d_ws, size_t ws_size,
                              hipStream_t stream) {
    const float* x = (const float*)d_in[0];
    float* out = (float*)d_out;
    dim3 grid(L_DIM / CHUNK, B_DIM);
    pool_feat_kernel<<<grid, dim3(T), 0, stream>>>(x, out);
}

// Round 3
// 33.580 us; speedup vs baseline: 1.0536x; 1.0536x over previous
//
#include <hip/hip_runtime.h>

#define B_DIM 256
#define L_DIM 32768
#define CHUNK 2048
#define HALO  100
#define NTOT  (CHUNK + 2*HALO)   // 2248
#define NG    (NTOT/4)           // 562 float4 groups
#define T     256
#define EPT   9                  // ceil(NTOT / T)

__global__ __launch_bounds__(T) void pool_feat_kernel(const float* __restrict__ x,
                                                      float* __restrict__ out) {
    const int row    = blockIdx.y;
    const int chunk0 = blockIdx.x * CHUNK;
    const int tid    = threadIdx.x;

    // sA doubles as the raw-x staging buffer (phase 1/2) and the a-cumsum
    // (phase 4+): safe because each thread overwrites only the segment it
    // alone read, with the wave-total barrier in between.
    __shared__ __align__(16) float sA[NTOT];
    __shared__ __align__(16) float sB[NTOT];
    __shared__ float waveA[4];
    __shared__ float waveB[4];

    const float* xr = x + (size_t)row * L_DIM;

    // Phase 1: coalesced float4 load of raw x (zero-fill outside the row)
    for (int g = tid; g < NG; g += T) {
        const int c = chunk0 - HALO + 4 * g;   // 4-aligned (HALO%4==0)
        float4 v;
        if (c >= 0 && c + 3 < L_DIM) {
            v = *reinterpret_cast<const float4*>(xr + c);
        } else {
            v.x = (c + 0 >= 0 && c + 0 < L_DIM) ? xr[c + 0] : 0.0f;
            v.y = (c + 1 >= 0 && c + 1 < L_DIM) ? xr[c + 1] : 0.0f;
            v.z = (c + 2 >= 0 && c + 2 < L_DIM) ? xr[c + 2] : 0.0f;
            v.w = (c + 3 >= 0 && c + 3 < L_DIM) ? xr[c + 3] : 0.0f;
        }
        *reinterpret_cast<float4*>(&sA[4 * g]) = v;
    }
    __syncthreads();

    // Phase 2: per-thread transform + inclusive cumsum, entirely in registers
    const int s0 = tid * EPT;
    float ra[EPT], rb[EPT];
    float runA = 0.0f, runB = 0.0f;
    #pragma unroll
    for (int j = 0; j < EPT; ++j) {
        const int idx = s0 + j;
        const float v = (idx < NTOT) ? sA[idx] : 0.0f;
        runA += __logf(fmaxf(1.0f, 1.0f + v));
        runB += __logf(fmaxf(1.0f, 1.0f - v));
        ra[j] = runA; rb[j] = runB;
    }

    // Phase 3: scan segment totals across the block (wave shuffle + wave totals)
    float vA = runA, vB = runB;
    const int lane = tid & 63;
    const int wid  = tid >> 6;
    #pragma unroll
    for (int d = 1; d < 64; d <<= 1) {
        float uA = __shfl_up(vA, d);
        float uB = __shfl_up(vB, d);
        if (lane >= d) { vA += uA; vB += uB; }
    }
    if (lane == 63) { waveA[wid] = vA; waveB[wid] = vB; }
    __syncthreads();
    float offA = vA - runA;   // exclusive prefix within wave
    float offB = vB - runB;
    #pragma unroll
    for (int w = 0; w < 3; ++w) {
        if (w < wid) { offA += waveA[w]; offB += waveB[w]; }
    }

    // Phase 4: single write pass of the final cumsum into LDS
    #pragma unroll
    for (int j = 0; j < EPT; ++j) {
        const int idx = s0 + j;
        if (idx < NTOT) { sA[idx] = ra[j] + offA; sB[idx] = rb[j] + offB; }
    }
    __syncthreads();

    // Phase 5: windowed sums from cumsum; float4 stores to 4 output planes.
    //   sum199_i = cs[i+199] - cs[i];  sum3_i = cs[i+101] - cs[i+98]
    const float inv3   = 1.0f / 3.0f;
    const float inv199 = 1.0f / 199.0f;
    float* ob = out + (size_t)row * 4u * L_DIM + chunk0;
    #pragma unroll
    for (int it = 0; it < CHUNK / (4 * T); ++it) {   // 2 iterations
        const int i0 = 4 * (tid + it * T);
        float4 r0, r1, r2, r3;
        #pragma unroll
        for (int u = 0; u < 4; ++u) {
            const int i = i0 + u;
            float s199a = sA[i + 199] - sA[i];
            float s3a   = sA[i + 101] - sA[i + 98];
            float s199b = sB[i + 199] - sB[i];
            float s3b   = sB[i + 101] - sB[i + 98];
            float a0 = s3a * inv3, a5 = s199a * inv199;
            float b0 = s3b * inv3, b5 = s199b * inv199;
            reinterpret_cast<float*>(&r0)[u] = a0 - a5;
            reinterpret_cast<float*>(&r1)[u] = a0;
            reinterpret_cast<float*>(&r2)[u] = b0 - b5;
            reinterpret_cast<float*>(&r3)[u] = b0;
        }
        *reinterpret_cast<float4*>(ob + 0 * (size_t)L_DIM + i0) = r0;
        *reinterpret_cast<float4*>(ob + 1 * (size_t)L_DIM + i0) = r1;
        *reinterpret_cast<float4*>(ob + 2 * (size_t)L_DIM + i0) = r2;
        *reinterpret_cast<float4*>(ob + 3 * (size_t)L_DIM + i0) = r3;
    }
}

extern "C" void kernel_launch(void* const* d_in, const int* in_sizes, int n_in,
                              void* d_out, int out_size, void* d_ws, size_t ws_size,
                              hipStream_t stream) {
    const float* x = (const float*)d_in[0];
    float* out = (float*)d_out;
    dim3 grid(L_DIM / CHUNK, B_DIM);
    pool_feat_kernel<<<grid, dim3(T), 0, stream>>>(x, out);
}

// Round 5
// 32.273 us; speedup vs baseline: 1.0962x; 1.0405x over previous
//
#include <hip/hip_runtime.h>

#define B_DIM 256
#define L_DIM 32768
#define CHUNK 2048
#define HALO  100
#define NTOT  (CHUNK + 2*HALO)   // 2248
#define NG    (NTOT/4)           // 562 float4 groups
#define T     256
#define EPT   9                  // ceil(NTOT / T)

typedef float fx4 __attribute__((ext_vector_type(4)));

__global__ __launch_bounds__(T) void pool_feat_kernel(const float* __restrict__ x,
                                                      float* __restrict__ out) {
    const int row    = blockIdx.y;
    const int chunk0 = blockIdx.x * CHUNK;
    const int tid    = threadIdx.x;

    // sA doubles as raw-x staging (phase 1/2) and the a-cumsum (phase 4+):
    // each thread overwrites only the segment it alone read, barrier between.
    __shared__ __align__(16) float sA[NTOT];
    __shared__ __align__(16) float sB[NTOT];
    __shared__ float waveA[4];
    __shared__ float waveB[4];

    const float* xr = x + (size_t)row * L_DIM;

    // Phase 1: coalesced float4 load of raw x (zero-fill outside the row)
    for (int g = tid; g < NG; g += T) {
        const int c = chunk0 - HALO + 4 * g;   // 4-aligned (HALO%4==0)
        fx4 v;
        if (c >= 0 && c + 3 < L_DIM) {
            v = *reinterpret_cast<const fx4*>(xr + c);
        } else {
            v.x = (c + 0 >= 0 && c + 0 < L_DIM) ? xr[c + 0] : 0.0f;
            v.y = (c + 1 >= 0 && c + 1 < L_DIM) ? xr[c + 1] : 0.0f;
            v.z = (c + 2 >= 0 && c + 2 < L_DIM) ? xr[c + 2] : 0.0f;
            v.w = (c + 3 >= 0 && c + 3 < L_DIM) ? xr[c + 3] : 0.0f;
        }
        *reinterpret_cast<fx4*>(&sA[4 * g]) = v;
    }
    __syncthreads();

    // Phase 2: per-thread transform + inclusive cumsum, in registers
    const int s0 = tid * EPT;
    float ra[EPT], rb[EPT];
    float runA = 0.0f, runB = 0.0f;
    #pragma unroll
    for (int j = 0; j < EPT; ++j) {
        const int idx = s0 + j;
        const float v = (idx < NTOT) ? sA[idx] : 0.0f;
        runA += __logf(fmaxf(1.0f, 1.0f + v));
        runB += __logf(fmaxf(1.0f, 1.0f - v));
        ra[j] = runA; rb[j] = runB;
    }

    // Phase 3: scan segment totals across the block
    float vA = runA, vB = runB;
    const int lane = tid & 63;
    const int wid  = tid >> 6;
    #pragma unroll
    for (int d = 1; d < 64; d <<= 1) {
        float uA = __shfl_up(vA, d);
        float uB = __shfl_up(vB, d);
        if (lane >= d) { vA += uA; vB += uB; }
    }
    if (lane == 63) { waveA[wid] = vA; waveB[wid] = vB; }
    __syncthreads();
    float offA = vA - runA;   // exclusive prefix within wave
    float offB = vB - runB;
    #pragma unroll
    for (int w = 0; w < 3; ++w) {
        if (w < wid) { offA += waveA[w]; offB += waveB[w]; }
    }

    // Phase 4: single write pass of the final cumsum into LDS
    #pragma unroll
    for (int j = 0; j < EPT; ++j) {
        const int idx = s0 + j;
        if (idx < NTOT) { sA[idx] = ra[j] + offA; sB[idx] = rb[j] + offB; }
    }
    __syncthreads();

    // Phase 5: windows via aligned ds_read_b128 only (conflict-free pattern),
    // shifted windows assembled by register selects from adjacent float4s.
    //   cs[i]     -> L0[u]                  (L0 = cs[i0+0..3])
    //   cs[i+98]  -> {L1.z,L1.w,L2.x,L2.y}  (L1 = cs[i0+96..99], L2 = cs[i0+100..103])
    //   cs[i+101] -> {L2.y,L2.z,L2.w,L3.x}  (L3 = cs[i0+104..107])
    //   cs[i+199] -> {L4.w,L5.x,L5.y,L5.z}  (L4 = cs[i0+196..199], L5 = cs[i0+200..203])
    const float inv3   = 1.0f / 3.0f;
    const float inv199 = 1.0f / 199.0f;
    float* ob = out + (size_t)row * 4u * L_DIM + chunk0;
    #pragma unroll
    for (int it = 0; it < CHUNK / (4 * T); ++it) {   // 2 iterations
        const int i0 = 4 * (tid + it * T);
        fx4 r0, r1, r2, r3;
        #pragma unroll
        for (int arr = 0; arr < 2; ++arr) {
            const float* s = arr ? sB : sA;
            const fx4 L0 = *reinterpret_cast<const fx4*>(s + i0);
            const fx4 L1 = *reinterpret_cast<const fx4*>(s + i0 + 96);
            const fx4 L2 = *reinterpret_cast<const fx4*>(s + i0 + 100);
            const fx4 L3 = *reinterpret_cast<const fx4*>(s + i0 + 104);
            const fx4 L4 = *reinterpret_cast<const fx4*>(s + i0 + 196);
            const fx4 L5 = *reinterpret_cast<const fx4*>(s + i0 + 200);
            const float csI[4]   = {L0.x, L0.y, L0.z, L0.w};
            const float cs98[4]  = {L1.z, L1.w, L2.x, L2.y};
            const float cs101[4] = {L2.y, L2.z, L2.w, L3.x};
            const float cs199[4] = {L4.w, L5.x, L5.y, L5.z};
            fx4& rs = arr ? r3 : r1;   // plain k=3 pool
            fx4& rd = arr ? r2 : r0;   // k=3 - k=199
            #pragma unroll
            for (int u = 0; u < 4; ++u) {
                const float p0 = (cs101[u] - cs98[u]) * inv3;
                const float p5 = (cs199[u] - csI[u]) * inv199;
                rs[u] = p0;
                rd[u] = p0 - p5;
            }
        }
        __builtin_nontemporal_store(r0, reinterpret_cast<fx4*>(ob + 0 * (size_t)L_DIM + i0));
        __builtin_nontemporal_store(r1, reinterpret_cast<fx4*>(ob + 1 * (size_t)L_DIM + i0));
        __builtin_nontemporal_store(r2, reinterpret_cast<fx4*>(ob + 2 * (size_t)L_DIM + i0));
        __builtin_nontemporal_store(r3, reinterpret_cast<fx4*>(ob + 3 * (size_t)L_DIM + i0));
    }
}

extern "C" void kernel_launch(void* const* d_in, const int* in_sizes, int n_in,
                              void* d_out, int out_size, void* d_ws, size_t ws_size,
                              hipStream_t stream) {
    const float* x = (const float*)d_in[0];
    float* out = (float*)d_out;
    dim3 grid(L_DIM / CHUNK, B_DIM);
    pool_feat_kernel<<<grid, dim3(T), 0, stream>>>(x, out);
}